// Round 15
// baseline (258.171 us; speedup 1.0000x reference)
//
#include <hip/hip_runtime.h>
#include <math.h>

#define B_   256
#define S_   512
#define NQ_  1000
#define MEM_ 20
#define DK_  50
#define DV_  200
#define FC_  50
#define CHK  16             // chunks for parallel scan (validated sweet spot)
#define CLEN (S_/CHK)       // 32 steps per chunk
#define NKS  7              // K-steps for MFMA (K = 224)
#define XS_STRIDE 232       // LDS row stride in bf16 (224 + 8 pad)
#define CORR_STRIDE 12      // uints per corr row (10 used + 2 pad -> 48B)
#define EA_NT 28            // n-tiles in ea GEMM (N = 448: [ew 200|pad 8|aw 200|pad 40])
#define NB_CORR  4
#define NB_WPK2  ((NKS*EA_NT+3)/4)       // 49 blocks of 4 wave-tasks
#define PREP1_BLOCKS (NB_CORR+NB_WPK2)
#define EA_BLOCKS ((2*NQ_+1+31)/32)      // 63
#define NB_WPACK 7
#define NB_HQ    251
#define MM_BLOCKS (B_*CHK)        // 4096
#define SCANA_BLOCKS (B_*(CHK-1)) // 3840
#define SCANA_TOTAL (SCANA_BLOCKS+NB_WPACK+NB_HQ)

typedef __attribute__((ext_vector_type(8))) short bf16x8_t;
typedef __attribute__((ext_vector_type(4))) float f32x4_t;
typedef __attribute__((ext_vector_type(2))) _Float16 f16x2_t;

static __device__ __forceinline__ f16x2_t h2(unsigned u){ return __builtin_bit_cast(f16x2_t, u); }
static __device__ __forceinline__ unsigned h2u(f16x2_t v){ return __builtin_bit_cast(unsigned, v); }
static __device__ __forceinline__ unsigned packh2(float x, float y){
  unsigned short bx = __builtin_bit_cast(unsigned short, (_Float16)x);
  unsigned short by = __builtin_bit_cast(unsigned short, (_Float16)y);
  return (unsigned)bx | ((unsigned)by << 16);
}
static __device__ __forceinline__ f16x2_t pkfma16(f16x2_t a, f16x2_t b, f16x2_t c){
  return __builtin_elementwise_fma(a, b, c);     // -> v_pk_fma_f16 (full rate)
}

static __device__ __forceinline__ unsigned short f2bf(float f){
  unsigned u = __float_as_uint(f);
  unsigned r = u + 0x7fffu + ((u >> 16) & 1u);   // round-to-nearest-even
  return (unsigned short)(r >> 16);
}
static __device__ __forceinline__ float ftanh(float x){
  float e = __expf(2.f*x);
  return 1.f - 2.f*__builtin_amdgcn_rcpf(e+1.f);
}
static __device__ __forceinline__ float fsigm(float x){
  return __builtin_amdgcn_rcpf(1.f+__expf(-x));
}

// K0: prep1 — [0,4): corrH (f16 pairs); [4,53): pack W2=[ew|pad|aw|pad] bf16 fragments.
__global__ __launch_bounds__(256) void k_prep1(
    const float* __restrict__ qw, const float* __restrict__ mk,
    unsigned* __restrict__ corrH,
    const float* __restrict__ ew, const float* __restrict__ aw,
    unsigned short* __restrict__ Wfrag2){
  int blk = blockIdx.x;
  if(blk < NB_CORR){
    int q = blk*256 + threadIdx.x;
    if(q > NQ_) return;
    float qv[DK_];
    #pragma unroll
    for(int j=0;j<DK_;++j) qv[j] = qw[q*DK_+j];
    float s[MEM_]; float mx = -1e30f;
    #pragma unroll
    for(int m=0;m<MEM_;++m){
      float acc = 0.f;
      #pragma unroll
      for(int j=0;j<DK_;++j) acc = fmaf(qv[j], mk[m*DK_+j], acc);
      s[m] = acc; mx = fmaxf(mx, acc);
    }
    float sum = 0.f;
    #pragma unroll
    for(int m=0;m<MEM_;++m){ s[m] = __expf(s[m]-mx); sum += s[m]; }
    float inv = __builtin_amdgcn_rcpf(sum);
    #pragma unroll
    for(int i=0;i<MEM_/2;++i)
      corrH[q*CORR_STRIDE+i] = packh2(s[2*i]*inv, s[2*i+1]*inv);
  } else {
    int task = (blk-NB_CORR)*4 + (threadIdx.x >> 6);
    if(task >= NKS*EA_NT) return;
    int ks = task / EA_NT, nt = task % EA_NT;
    int lane = threadIdx.x & 63;
    int quad = lane >> 4, col = lane & 15;
    int n = nt*16 + col;
    unsigned short tmp[8];
    #pragma unroll
    for(int j=0;j<8;++j){
      int k = ks*32 + quad*8 + j;
      float w = 0.f;
      if(k < DV_){
        if(n < DV_)                      w = ew[k*DV_+n];
        else if(n >= 208 && n < 208+DV_) w = aw[k*DV_+(n-208)];
      }
      tmp[j] = f2bf(w);
    }
    uint4* dst = reinterpret_cast<uint4*>(Wfrag2 + ((size_t)(ks*EA_NT+nt)*64 + lane)*8);
    *dst = *reinterpret_cast<const uint4*>(tmp);
  }
}

// K0b: eaTab via MFMA — QA[2001x200] @ W2[200x448] (bf16, fp32 acc), fused
// sigmoid/tanh epilogue, broadcast-pair f16 store. Proven A/B/C layouts
// reused from scan_mm / k_wpack.
__global__ __launch_bounds__(256) void k_ea_mm(
    const float* __restrict__ qaw,
    const float* __restrict__ eb, const float* __restrict__ ab,
    const unsigned short* __restrict__ Wfrag2,
    unsigned* __restrict__ eaU){
  __shared__ unsigned short Xs[32*XS_STRIDE];   // 14,848 B
  const int R0 = blockIdx.x*32;
  for(int i=threadIdx.x; i<32*224; i+=256){
    int r = i/224, k = i - r*224;
    int row = R0 + r;
    float v = (k < DV_ && row <= 2*NQ_) ? qaw[(size_t)row*DV_+k] : 0.f;
    Xs[r*XS_STRIDE + k] = f2bf(v);
  }
  __syncthreads();

  const int wave = threadIdx.x >> 6;
  const int lane = threadIdx.x & 63;
  const int col  = lane & 15, quad = lane >> 4;
  const int rt   = wave & 1;
  const int nh   = wave >> 1;
  const int mrow = rt*16;

  for(int nt=nh; nt<EA_NT; nt+=2){
    f32x4_t acc = (f32x4_t){0.f,0.f,0.f,0.f};
    #pragma unroll
    for(int ks=0;ks<NKS;++ks){
      bf16x8_t a = *reinterpret_cast<const bf16x8_t*>(Xs + (mrow+col)*XS_STRIDE + quad*8 + ks*32);
      bf16x8_t bfr = *reinterpret_cast<const bf16x8_t*>(Wfrag2 + ((size_t)(ks*EA_NT+nt)*64 + lane)*8);
      acc = __builtin_amdgcn_mfma_f32_16x16x32_bf16(a, bfr, acc, 0, 0, 0);
    }
    int n = nt*16 + col;
    if(n < DV_){
      float bias = eb[n];
      #pragma unroll
      for(int reg=0;reg<4;++reg){
        int row = R0 + mrow + quad*4 + reg;
        if(row <= 2*NQ_){
          float v = fsigm(acc[reg] + bias);
          unsigned hv = (unsigned)__builtin_bit_cast(unsigned short, (_Float16)v) * 0x10001u;
          eaU[((size_t)row*DV_ + n)*2] = hv;        // (e,e)
        }
      }
    } else if(n >= 208 && n < 208+DV_){
      int dd = n - 208;
      float bias = ab[dd];
      #pragma unroll
      for(int reg=0;reg<4;++reg){
        int row = R0 + mrow + quad*4 + reg;
        if(row <= 2*NQ_){
          float v = ftanh(acc[reg] + bias);
          unsigned hv = (unsigned)__builtin_bit_cast(unsigned short, (_Float16)v) * 0x10001u;
          eaU[((size_t)row*DV_ + dd)*2 + 1] = hv;   // (a,a)
        }
      }
    }
  }
}

// K1: phase 1 — per-chunk affine (A,B), f16 packed math (full-rate), corr via
// scalar loads (readfirstlane); ROLLED loop, unroll 4 (r13 lesson: full unroll
// + hoisted loads => 750B/thread scratch spill). Trailing blocks: WpFrag/hq.
__global__ __launch_bounds__(256,8) void k_scanA(const int* __restrict__ qd,
    const int* __restrict__ qad,
    const unsigned* __restrict__ corrH,
    const uint2* __restrict__ eaTab,
    unsigned* __restrict__ ABu,
    const float* __restrict__ qw,
    const float* __restrict__ rw, const float* __restrict__ rb,
    const float* __restrict__ pw,
    unsigned short* __restrict__ WpFrag, float* __restrict__ pwPad,
    float* __restrict__ hq){
  const int blk = blockIdx.x;
  if(blk >= SCANA_BLOCKS){
    int xblk = blk - SCANA_BLOCKS;
    if(xblk < NB_WPACK){
      int ks = xblk;
      int nt = threadIdx.x >> 6;
      int lane = threadIdx.x & 63;
      int quad = lane >> 4, col = lane & 15;
      int n = nt*16 + col;
      unsigned short tmp[8];
      #pragma unroll
      for(int j=0;j<8;++j){
        int k = ks*32 + quad*8 + j;
        tmp[j] = (k < DV_ && n < FC_) ? f2bf(rw[k*FC_+n]) : (unsigned short)0;
      }
      uint4* dst = reinterpret_cast<uint4*>(WpFrag + ((size_t)(ks*4+nt)*64 + lane)*8);
      *dst = *reinterpret_cast<const uint4*>(tmp);
      if(ks == 0 && threadIdx.x < 64)
        pwPad[threadIdx.x] = (threadIdx.x < FC_) ? pw[threadIdx.x] : 0.f;
    } else {
      int idx = (xblk-NB_WPACK)*256 + threadIdx.x;
      int q = idx >> 6, n = idx & 63;
      if(q > NQ_) return;
      float v = 0.f;
      if(n < FC_){
        float acc = rb[n];
        #pragma unroll
        for(int j=0;j<DK_;++j)
          acc = fmaf(qw[q*DK_+j], rw[(DV_+j)*FC_+n], acc);
        v = acc;
      }
      hq[q*64+n] = v;
    }
    return;
  }

  const int b = blk / (CHK-1), c = blk % (CHK-1);
  const int d = threadIdx.x;
  const int dc = (d < DV_) ? d : DV_-1;
  const bool act = (d < DV_);
  const int* __restrict__ qp  = qd  + b*S_ + c*CLEN;
  const int* __restrict__ qap = qad + b*S_ + c*CLEN;

  const f16x2_t one2h = {(_Float16)1.f, (_Float16)1.f};
  f16x2_t A2[MEM_/2], B2[MEM_/2];
  #pragma unroll
  for(int i=0;i<MEM_/2;++i){ A2[i] = one2h; B2[i] = (f16x2_t){(_Float16)0.f,(_Float16)0.f}; }

  int q2   = qp[1];
  int qaT2 = qap[2];
  int qaT3 = qap[3];
  int q1s  = __builtin_amdgcn_readfirstlane(qp[0]);
  const unsigned* cp0 = corrH + q1s*CORR_STRIDE;
  uint4 ca = *(const uint4*)(cp0);
  uint4 cb = *(const uint4*)(cp0+4);
  uint2 cc = *(const uint2*)(cp0+8);
  uint2 ea  = eaTab[(size_t)qap[0]*DV_ + dc];
  uint2 ean = eaTab[(size_t)qap[1]*DV_ + dc];

  #pragma unroll 4
  for(int t=0;t<CLEN;++t){
    int t2 = (t+2 < CLEN) ? t+2 : CLEN-1;
    int t4 = (t+4 < CLEN) ? t+4 : CLEN-1;
    int q3 = qp[t2];
    int qaN = qap[t4];
    int qs = __builtin_amdgcn_readfirstlane(q2);
    const unsigned* cpn_ = corrH + qs*CORR_STRIDE;
    uint4 na = *(const uint4*)(cpn_);
    uint4 nb = *(const uint4*)(cpn_+4);
    uint2 nc = *(const uint2*)(cpn_+8);
    uint2 eann = eaTab[(size_t)qaT2*DV_ + dc];

    const f16x2_t ee = h2(ea.x), aa = h2(ea.y);
    #define UPDA(u, i) { \
      f16x2_t cp = h2(u); \
      f16x2_t al = pkfma16(-cp, ee, one2h); \
      f16x2_t be = cp*aa; \
      A2[i] = A2[i]*al; \
      B2[i] = pkfma16(al, B2[i], be); }
    UPDA(ca.x, 0)  UPDA(ca.y, 1)  UPDA(ca.z, 2)  UPDA(ca.w, 3)
    UPDA(cb.x, 4)  UPDA(cb.y, 5)  UPDA(cb.z, 6)  UPDA(cb.w, 7)
    UPDA(cc.x, 8)  UPDA(cc.y, 9)
    #undef UPDA

    ca=na; cb=nb; cc=nc;
    ea=ean; ean=eann;
    q2=q3; qaT2=qaT3; qaT3=qaN;
  }
  if(act){
    unsigned* base = ABu + ((size_t)(b*(CHK-1) + c)*MEM_)*DV_ + d;
    #pragma unroll
    for(int i=0;i<MEM_/2;++i){
      unsigned a01 = h2u(A2[i]);
      unsigned b01 = h2u(B2[i]);
      base[(size_t)(2*i)*DV_]   = (a01 & 0xffffu) | (b01 << 16);
      base[(size_t)(2*i+1)*DV_] = (a01 >> 16)     | (b01 & 0xffff0000u);
    }
  }
}

// K2: prefix — per (b, m-pair, d): compose chunk transforms (fp32), write
// chunk-start Mv as packed f16 pairs for c>=1 (c==0 blocks read mv0 directly).
__global__ __launch_bounds__(256) void k_prefix(const float* __restrict__ mv0,
    const unsigned* __restrict__ ABu, unsigned* __restrict__ Mv0p){
  int i = blockIdx.x*256 + threadIdx.x;
  if(i >= B_*(MEM_/2)*DV_) return;
  int d = i % DV_;
  int p = (i / DV_) % (MEM_/2);
  int b = i / (DV_*(MEM_/2));
  float MvE = mv0[(2*p)*DV_+d];
  float MvO = mv0[(2*p+1)*DV_+d];
  #pragma unroll
  for(int c=1;c<CHK;++c){
    unsigned vE = ABu[((size_t)(b*(CHK-1) + (c-1))*MEM_ + 2*p)*DV_ + d];
    unsigned vO = ABu[((size_t)(b*(CHK-1) + (c-1))*MEM_ + 2*p+1)*DV_ + d];
    MvE = fmaf((float)h2(vE)[0], MvE, (float)h2(vE)[1]);
    MvO = fmaf((float)h2(vO)[0], MvO, (float)h2(vO)[1]);
    Mv0p[((size_t)(b*CHK + c)*(MEM_/2) + p)*DV_ + d] = packh2(MvE, MvO);
  }
}

// K3: fused phase-2 scan (f16 pk-fma + v_dot2 f32-acc) + MFMA readout + epilogue.
// ROLLED loop unroll 4 (r13: full unroll spills). Scan state dies before MFMA
// phase (r10: overlapping lifetimes spill). Plain per-block partial stores —
// NO atomics/fences (r6/r7: per-block device-scope fences nuke per-XCD L2).
__global__ __launch_bounds__(256,8) void k_scan_mm(const int* __restrict__ qd,
    const int* __restrict__ qad,
    const unsigned* __restrict__ corrH,
    const uint2* __restrict__ eaTab,
    const float* __restrict__ mv0,
    const unsigned* __restrict__ Mv0p,
    const unsigned short* __restrict__ WpFrag,
    const float* __restrict__ hq,
    const float* __restrict__ pwPad, const float* __restrict__ pb,
    const float* __restrict__ target,
    float* __restrict__ out, float2* __restrict__ partials){
  __shared__ unsigned short Xs[CLEN*XS_STRIDE];   // 14,848 B
  __shared__ float sred[2][2][16];
  __shared__ float sbce[4];

  const int blk = blockIdx.x;
  const int b = blk >> 4, c = blk & (CHK-1);
  const int d = threadIdx.x;
  const int dc = (d < DV_) ? d : DV_-1;
  const bool act = (d < DV_);
  const bool padw = (d < 224);
  const int* __restrict__ qp  = qd  + b*S_ + c*CLEN;
  const int* __restrict__ qap = qad + b*S_ + c*CLEN;

  const int wave = threadIdx.x >> 6;
  const int lane = threadIdx.x & 63;
  const int col  = lane & 15, quad = lane >> 4;
  const int rt   = wave & 1;
  const int nh   = wave >> 1;
  const int mbase = rt*16;

  int qpre[4];
  #pragma unroll
  for(int reg=0;reg<4;++reg) qpre[reg] = qp[mbase + quad*4 + reg];

  f16x2_t Mv2[MEM_/2];
  if(c == 0){
    #pragma unroll
    for(int i=0;i<MEM_/2;++i)
      Mv2[i] = (f16x2_t){ (_Float16)mv0[(2*i)*DV_+dc], (_Float16)mv0[(2*i+1)*DV_+dc] };
  } else {
    const unsigned* base = Mv0p + ((size_t)(b*CHK + c)*(MEM_/2))*DV_ + dc;
    #pragma unroll
    for(int i=0;i<MEM_/2;++i)
      Mv2[i] = h2(base[(size_t)i*DV_]);
  }

  int q2   = qp[1];
  int qaT2 = qap[2];
  int qaT3 = qap[3];
  int q1s  = __builtin_amdgcn_readfirstlane(qp[0]);
  const unsigned* cp0 = corrH + q1s*CORR_STRIDE;
  uint4 ca = *(const uint4*)(cp0);
  uint4 cb = *(const uint4*)(cp0+4);
  uint2 cc = *(const uint2*)(cp0+8);
  uint2 ea  = eaTab[(size_t)qap[0]*DV_ + dc];
  uint2 ean = eaTab[(size_t)qap[1]*DV_ + dc];

  #pragma unroll 4
  for(int t=0;t<CLEN;++t){
    int t2 = (t+2 < CLEN) ? t+2 : CLEN-1;
    int t4 = (t+4 < CLEN) ? t+4 : CLEN-1;
    int q3 = qp[t2];
    int qaN = qap[t4];
    int qs = __builtin_amdgcn_readfirstlane(q2);
    const unsigned* cpn_ = corrH + qs*CORR_STRIDE;
    uint4 na = *(const uint4*)(cpn_);
    uint4 nb = *(const uint4*)(cpn_+4);
    uint2 nc = *(const uint2*)(cpn_+8);
    uint2 eann = eaTab[(size_t)qaT2*DV_ + dc];

    const f16x2_t ee = h2(ea.x), aa = h2(ea.y);
    float rd0 = 0.f, rd1 = 0.f;
    #define UPD2(u, i, acc) { \
      f16x2_t cp = h2(u); \
      acc = __builtin_amdgcn_fdot2(cp, Mv2[i], acc, false); \
      f16x2_t tt = pkfma16(-Mv2[i], ee, aa); \
      Mv2[i] = pkfma16(cp, tt, Mv2[i]); }
    UPD2(ca.x, 0, rd0)  UPD2(ca.y, 1, rd1)  UPD2(ca.z, 2, rd0)  UPD2(ca.w, 3, rd1)
    UPD2(cb.x, 4, rd0)  UPD2(cb.y, 5, rd1)  UPD2(cb.z, 6, rd0)  UPD2(cb.w, 7, rd1)
    UPD2(cc.x, 8, rd0)  UPD2(cc.y, 9, rd1)
    #undef UPD2

    if(padw) Xs[t*XS_STRIDE + d] = act ? f2bf(rd0+rd1) : (unsigned short)0;

    ca=na; cb=nb; cc=nc;
    ea=ean; ean=eann;
    q2=q3; qaT2=qaT3; qaT3=qaN;
  }
  __syncthreads();

  // hq prefetch — issued before the MFMA loop so the 14 MFMAs hide the latency
  float hqv[4][2];
  #pragma unroll
  for(int reg=0;reg<4;++reg)
    #pragma unroll
    for(int j=0;j<2;++j)
      hqv[reg][j] = hq[qpre[reg]*64 + (nh*2+j)*16 + col];

  f32x4_t acc[2];
  acc[0] = (f32x4_t){0.f,0.f,0.f,0.f};
  acc[1] = (f32x4_t){0.f,0.f,0.f,0.f};

  #pragma unroll
  for(int ks=0;ks<NKS;++ks){
    bf16x8_t a = *reinterpret_cast<const bf16x8_t*>(Xs + (mbase+col)*XS_STRIDE + quad*8 + ks*32);
    #pragma unroll
    for(int j=0;j<2;++j){
      int nt = nh*2 + j;
      bf16x8_t bfr = *reinterpret_cast<const bf16x8_t*>(WpFrag + ((size_t)(ks*4+nt)*64 + lane)*8);
      acc[j] = __builtin_amdgcn_mfma_f32_16x16x32_bf16(a, bfr, acc[j], 0, 0, 0);
    }
  }

  float part[4];
  #pragma unroll
  for(int reg=0;reg<4;++reg){
    float s = 0.f;
    #pragma unroll
    for(int j=0;j<2;++j){
      int n = (nh*2+j)*16 + col;
      float h = acc[j][reg] + hqv[reg][j];
      s = fmaf(pwPad[n], ftanh(h), s);
    }
    part[reg] = s;
  }
  #pragma unroll
  for(int off=1; off<16; off<<=1){
    #pragma unroll
    for(int reg=0;reg<4;++reg) part[reg] += __shfl_xor(part[reg], off, 64);
  }
  if(col == 0){
    #pragma unroll
    for(int reg=0;reg<4;++reg) sred[rt][nh][quad*4+reg] = part[reg];
  }
  __syncthreads();

  float bce = 0.f, cnt = 0.f;
  if(nh == 0 && col == 0){
    float pbv = pb[0];
    #pragma unroll
    for(int reg=0;reg<4;++reg){
      int idx = quad*4 + reg;
      int mloc = mbase + idx;
      int row = b*S_ + c*CLEN + mloc;
      float logit = sred[rt][0][idx] + sred[rt][1][idx] + pbv;
      out[1+row] = fsigm(logit);
      float t = target[row];
      if(t >= 0.f){
        cnt += 1.f;
        bce += fmaxf(logit,0.f) - logit*t + log1pf(__expf(-fabsf(logit)));
      }
    }
  }
  bce += __shfl_xor(bce, 16, 64); cnt += __shfl_xor(cnt, 16, 64);
  bce += __shfl_xor(bce, 32, 64); cnt += __shfl_xor(cnt, 32, 64);
  if(lane == 0 && nh == 0){ sbce[wave] = bce; sbce[2+wave] = cnt; }
  __syncthreads();
  if(threadIdx.x == 0)
    partials[blk] = make_float2(sbce[0]+sbce[1], sbce[2]+sbce[3]);
}

// K4: reduce per-block partials -> loss
__global__ __launch_bounds__(256) void k_fin(const float2* __restrict__ partials,
                                             float* __restrict__ out){
  float bce = 0.f, cnt = 0.f;
  for(int i=threadIdx.x; i<MM_BLOCKS; i+=256){
    float2 p = partials[i];
    bce += p.x; cnt += p.y;
  }
  #pragma unroll
  for(int off=32; off>0; off>>=1){
    bce += __shfl_down(bce, off, 64);
    cnt += __shfl_down(cnt, off, 64);
  }
  __shared__ float sb[4], sc[4];
  int w = threadIdx.x >> 6;
  if((threadIdx.x & 63) == 0){ sb[w] = bce; sc[w] = cnt; }
  __syncthreads();
  if(threadIdx.x == 0){
    float Bt = sb[0]+sb[1]+sb[2]+sb[3];
    float Ct = sc[0]+sc[1]+sc[2]+sc[3];
    out[0] = Bt / fmaxf(Ct, 1.f);
  }
}

extern "C" void kernel_launch(void* const* d_in, const int* in_sizes, int n_in,
                              void* d_out, int out_size, void* d_ws, size_t ws_size,
                              hipStream_t stream){
  const int*   qd     = (const int*)d_in[0];
  const int*   qad    = (const int*)d_in[1];
  const float* target = (const float*)d_in[2];
  const float* qw     = (const float*)d_in[3];
  const float* qaw    = (const float*)d_in[4];
  const float* mk     = (const float*)d_in[5];
  const float* mv0    = (const float*)d_in[6];
  const float* ew     = (const float*)d_in[7];
  const float* eb     = (const float*)d_in[8];
  const float* aw     = (const float*)d_in[9];
  const float* ab     = (const float*)d_in[10];
  const float* rw     = (const float*)d_in[11];
  const float* rb     = (const float*)d_in[12];
  const float* pw     = (const float*)d_in[13];
  const float* pb     = (const float*)d_in[14];
  float* out = (float*)d_out;

  char* ws = (char*)d_ws;
  size_t off = 0;
  float2* partials = (float2*)(ws + off);            off += (size_t)MM_BLOCKS*8;
  unsigned* corrH = (unsigned*)(ws + off);           off += (((size_t)(NQ_+1)*CORR_STRIDE*4 + 255)/256)*256;
  uint2* eaTab    = (uint2*)(ws + off);              off += (((size_t)(2*NQ_+1)*DV_*8 + 255)/256)*256;
  unsigned* ABu   = (unsigned*)(ws + off);           off += (size_t)SCANA_BLOCKS*MEM_*DV_*4;
  unsigned* Mv0p  = (unsigned*)(ws + off);           off += (size_t)MM_BLOCKS*(MEM_/2)*DV_*4;
  unsigned short* WpFrag = (unsigned short*)(ws + off); off += ((size_t)NKS*4*64*8*2 + 255)/256*256;
  unsigned short* Wfrag2 = (unsigned short*)(ws + off); off += ((size_t)NKS*EA_NT*64*8*2 + 255)/256*256;
  float* pwPad    = (float*)(ws + off);              off += 256;
  float* hq       = (float*)(ws + off);              off += (size_t)(NQ_+1)*64*4;

  k_prep1<<<dim3(PREP1_BLOCKS), dim3(256), 0, stream>>>(qw, mk, corrH, ew, aw, Wfrag2);
  k_ea_mm<<<dim3(EA_BLOCKS), dim3(256), 0, stream>>>(qaw, eb, ab, Wfrag2, (unsigned*)eaTab);
  k_scanA<<<dim3(SCANA_TOTAL), dim3(256), 0, stream>>>(qd, qad, corrH, eaTab,
                                                       ABu, qw, rw, rb, pw, WpFrag, pwPad, hq);
  k_prefix<<<dim3((B_*(MEM_/2)*DV_+255)/256), dim3(256), 0, stream>>>(mv0, ABu, Mv0p);
  k_scan_mm<<<dim3(MM_BLOCKS), dim3(256), 0, stream>>>(qd, qad, corrH, eaTab,
                                                       mv0, Mv0p, WpFrag, hq, pwPad, pb, target, out, partials);
  k_fin<<<dim3(1), dim3(256), 0, stream>>>(partials, out);
}

// Round 16
// 223.097 us; speedup vs baseline: 1.1572x; 1.1572x over previous
//
#include <hip/hip_runtime.h>
#include <math.h>

#define B_   256
#define S_   512
#define NQ_  1000
#define MEM_ 20
#define DK_  50
#define DV_  200
#define FC_  50
#define RPB  4
#define CHK  16             // chunks for parallel scan (validated sweet spot)
#define CLEN (S_/CHK)       // 32 steps per chunk
#define NKS  7              // K-steps for MFMA (K = 224 = 200 reads + 24 zero)
#define XS_STRIDE 232       // LDS row stride in bf16 (224 + 8 pad)
#define CORR_STRIDE 12      // uints per corr row (10 used + 2 pad -> 48B)
#define NB_EA    ((2*NQ_+1+RPB-1)/RPB)   // 501
#define NB_CORR  4
#define NB_WPACK 7
#define NB_HQ    251
#define PREP1_BLOCKS (NB_EA+NB_CORR)
#define MM_BLOCKS (B_*CHK)        // 4096
#define SCANA_BLOCKS (B_*(CHK-1)) // 3840
#define SCANA_TOTAL (SCANA_BLOCKS+NB_WPACK+NB_HQ)

typedef __attribute__((ext_vector_type(8))) short bf16x8_t;
typedef __attribute__((ext_vector_type(4))) float f32x4_t;
typedef __attribute__((ext_vector_type(2))) _Float16 f16x2_t;

static __device__ __forceinline__ f16x2_t h2(unsigned u){ return __builtin_bit_cast(f16x2_t, u); }
static __device__ __forceinline__ unsigned h2u(f16x2_t v){ return __builtin_bit_cast(unsigned, v); }
static __device__ __forceinline__ unsigned packh2(float x, float y){
  unsigned short bx = __builtin_bit_cast(unsigned short, (_Float16)x);
  unsigned short by = __builtin_bit_cast(unsigned short, (_Float16)y);
  return (unsigned)bx | ((unsigned)by << 16);
}
static __device__ __forceinline__ f16x2_t pkfma16(f16x2_t a, f16x2_t b, f16x2_t c){
  return __builtin_elementwise_fma(a, b, c);     // -> v_pk_fma_f16 (full rate)
}

static __device__ __forceinline__ unsigned short f2bf(float f){
  unsigned u = __float_as_uint(f);
  unsigned r = u + 0x7fffu + ((u >> 16) & 1u);   // round-to-nearest-even
  return (unsigned short)(r >> 16);
}
static __device__ __forceinline__ float ftanh(float x){
  float e = __expf(2.f*x);
  return 1.f - 2.f*__builtin_amdgcn_rcpf(e+1.f);
}
static __device__ __forceinline__ float fsigm(float x){
  return __builtin_amdgcn_rcpf(1.f+__expf(-x));
}

// K0: prep1 — [0,501): eaTab (f16 pre-broadcast pairs); [501,505): corrH (f16 pairs).
// (r15 lesson: do NOT split this into small-grid GEMM dispatches — two serialized
// ~60-block launches idle the machine and strided stores eat the MFMA gain.)
__global__ __launch_bounds__(256) void k_prep1(
    const float* __restrict__ qaw,
    const float* __restrict__ ew, const float* __restrict__ eb,
    const float* __restrict__ aw, const float* __restrict__ ab,
    uint2* __restrict__ eaTab,
    const float* __restrict__ qw, const float* __restrict__ mk,
    unsigned* __restrict__ corrH){
  __shared__ float qa[RPB*DV_];
  int blk = blockIdx.x;
  if(blk < NB_EA){
    int row0 = blk*RPB;
    for(int i=threadIdx.x; i<RPB*DV_; i+=256){
      int r = i/DV_, cc = i - r*DV_;
      int row = row0 + r;
      qa[i] = (row <= 2*NQ_) ? qaw[row*DV_+cc] : 0.f;
    }
    __syncthreads();
    int d = threadIdx.x;
    if(d >= DV_) return;
    float accE[RPB], accA[RPB];
    #pragma unroll
    for(int r=0;r<RPB;++r){ accE[r] = eb[d]; accA[r] = ab[d]; }
    float we0 = ew[d], wa0 = aw[d];
    for(int j=0;j<DV_;++j){
      int jn = (j+1 < DV_) ? j+1 : j;
      float we1 = ew[jn*DV_+d];
      float wa1 = aw[jn*DV_+d];
      #pragma unroll
      for(int r=0;r<RPB;++r){
        float x = qa[r*DV_+j];
        accE[r] = fmaf(x, we0, accE[r]);
        accA[r] = fmaf(x, wa0, accA[r]);
      }
      we0 = we1; wa0 = wa1;
    }
    #pragma unroll
    for(int r=0;r<RPB;++r){
      int row = row0 + r;
      if(row <= 2*NQ_){
        unsigned he = (unsigned)__builtin_bit_cast(unsigned short, (_Float16)fsigm(accE[r]));
        unsigned ha = (unsigned)__builtin_bit_cast(unsigned short, (_Float16)ftanh(accA[r]));
        eaTab[(size_t)row*DV_+d] = make_uint2(he*0x10001u, ha*0x10001u);   // (e,e),(a,a)
      }
    }
  } else {
    int q = (blk-NB_EA)*256 + threadIdx.x;
    if(q > NQ_) return;
    float qv[DK_];
    #pragma unroll
    for(int j=0;j<DK_;++j) qv[j] = qw[q*DK_+j];
    float s[MEM_]; float mx = -1e30f;
    #pragma unroll
    for(int m=0;m<MEM_;++m){
      float acc = 0.f;
      #pragma unroll
      for(int j=0;j<DK_;++j) acc = fmaf(qv[j], mk[m*DK_+j], acc);
      s[m] = acc; mx = fmaxf(mx, acc);
    }
    float sum = 0.f;
    #pragma unroll
    for(int m=0;m<MEM_;++m){ s[m] = __expf(s[m]-mx); sum += s[m]; }
    float inv = __builtin_amdgcn_rcpf(sum);
    #pragma unroll
    for(int i=0;i<MEM_/2;++i)
      corrH[q*CORR_STRIDE+i] = packh2(s[2*i]*inv, s[2*i+1]*inv);
  }
}

// K1: phase 1 — per-chunk affine (A,B), f16 packed math (full-rate), corr via
// scalar loads (readfirstlane); ROLLED loop, unroll 4 (r13 lesson: full unroll
// + hoisted loads => 750B/thread scratch spill). Trailing blocks: WpFrag/hq.
__global__ __launch_bounds__(256,8) void k_scanA(const int* __restrict__ qd,
    const int* __restrict__ qad,
    const unsigned* __restrict__ corrH,
    const uint2* __restrict__ eaTab,
    unsigned* __restrict__ ABu,
    const float* __restrict__ qw,
    const float* __restrict__ rw, const float* __restrict__ rb,
    const float* __restrict__ pw,
    unsigned short* __restrict__ WpFrag, float* __restrict__ pwPad,
    float* __restrict__ hq){
  const int blk = blockIdx.x;
  if(blk >= SCANA_BLOCKS){
    int xblk = blk - SCANA_BLOCKS;
    if(xblk < NB_WPACK){
      int ks = xblk;
      int nt = threadIdx.x >> 6;
      int lane = threadIdx.x & 63;
      int quad = lane >> 4, col = lane & 15;
      int n = nt*16 + col;
      unsigned short tmp[8];
      #pragma unroll
      for(int j=0;j<8;++j){
        int k = ks*32 + quad*8 + j;
        tmp[j] = (k < DV_ && n < FC_) ? f2bf(rw[k*FC_+n]) : (unsigned short)0;
      }
      uint4* dst = reinterpret_cast<uint4*>(WpFrag + ((size_t)(ks*4+nt)*64 + lane)*8);
      *dst = *reinterpret_cast<const uint4*>(tmp);
      if(ks == 0 && threadIdx.x < 64)
        pwPad[threadIdx.x] = (threadIdx.x < FC_) ? pw[threadIdx.x] : 0.f;
    } else {
      int idx = (xblk-NB_WPACK)*256 + threadIdx.x;
      int q = idx >> 6, n = idx & 63;
      if(q > NQ_) return;
      float v = 0.f;
      if(n < FC_){
        float acc = rb[n];
        #pragma unroll
        for(int j=0;j<DK_;++j)
          acc = fmaf(qw[q*DK_+j], rw[(DV_+j)*FC_+n], acc);
        v = acc;
      }
      hq[q*64+n] = v;
    }
    return;
  }

  const int b = blk / (CHK-1), c = blk % (CHK-1);
  const int d = threadIdx.x;
  const int dc = (d < DV_) ? d : DV_-1;
  const bool act = (d < DV_);
  const int* __restrict__ qp  = qd  + b*S_ + c*CLEN;
  const int* __restrict__ qap = qad + b*S_ + c*CLEN;

  const f16x2_t one2h = {(_Float16)1.f, (_Float16)1.f};
  f16x2_t A2[MEM_/2], B2[MEM_/2];
  #pragma unroll
  for(int i=0;i<MEM_/2;++i){ A2[i] = one2h; B2[i] = (f16x2_t){(_Float16)0.f,(_Float16)0.f}; }

  int q2   = qp[1];
  int qaT2 = qap[2];
  int qaT3 = qap[3];
  int q1s  = __builtin_amdgcn_readfirstlane(qp[0]);
  const unsigned* cp0 = corrH + q1s*CORR_STRIDE;
  uint4 ca = *(const uint4*)(cp0);
  uint4 cb = *(const uint4*)(cp0+4);
  uint2 cc = *(const uint2*)(cp0+8);
  uint2 ea  = eaTab[(size_t)qap[0]*DV_ + dc];
  uint2 ean = eaTab[(size_t)qap[1]*DV_ + dc];

  #pragma unroll 4
  for(int t=0;t<CLEN;++t){
    int t2 = (t+2 < CLEN) ? t+2 : CLEN-1;
    int t4 = (t+4 < CLEN) ? t+4 : CLEN-1;
    int q3 = qp[t2];
    int qaN = qap[t4];
    int qs = __builtin_amdgcn_readfirstlane(q2);
    const unsigned* cpn_ = corrH + qs*CORR_STRIDE;
    uint4 na = *(const uint4*)(cpn_);
    uint4 nb = *(const uint4*)(cpn_+4);
    uint2 nc = *(const uint2*)(cpn_+8);
    uint2 eann = eaTab[(size_t)qaT2*DV_ + dc];

    const f16x2_t ee = h2(ea.x), aa = h2(ea.y);
    #define UPDA(u, i) { \
      f16x2_t cp = h2(u); \
      f16x2_t al = pkfma16(-cp, ee, one2h); \
      f16x2_t be = cp*aa; \
      A2[i] = A2[i]*al; \
      B2[i] = pkfma16(al, B2[i], be); }
    UPDA(ca.x, 0)  UPDA(ca.y, 1)  UPDA(ca.z, 2)  UPDA(ca.w, 3)
    UPDA(cb.x, 4)  UPDA(cb.y, 5)  UPDA(cb.z, 6)  UPDA(cb.w, 7)
    UPDA(cc.x, 8)  UPDA(cc.y, 9)
    #undef UPDA

    ca=na; cb=nb; cc=nc;
    ea=ean; ean=eann;
    q2=q3; qaT2=qaT3; qaT3=qaN;
  }
  if(act){
    unsigned* base = ABu + ((size_t)(b*(CHK-1) + c)*MEM_)*DV_ + d;
    #pragma unroll
    for(int i=0;i<MEM_/2;++i){
      unsigned a01 = h2u(A2[i]);
      unsigned b01 = h2u(B2[i]);
      base[(size_t)(2*i)*DV_]   = (a01 & 0xffffu) | (b01 << 16);
      base[(size_t)(2*i+1)*DV_] = (a01 >> 16)     | (b01 & 0xffff0000u);
    }
  }
}

// K2: prefix — per (b, m-pair, d): compose chunk transforms (fp32), write
// chunk-start Mv as packed f16 pairs for c>=1 (c==0 blocks read mv0 directly).
__global__ __launch_bounds__(256) void k_prefix(const float* __restrict__ mv0,
    const unsigned* __restrict__ ABu, unsigned* __restrict__ Mv0p){
  int i = blockIdx.x*256 + threadIdx.x;
  if(i >= B_*(MEM_/2)*DV_) return;
  int d = i % DV_;
  int p = (i / DV_) % (MEM_/2);
  int b = i / (DV_*(MEM_/2));
  float MvE = mv0[(2*p)*DV_+d];
  float MvO = mv0[(2*p+1)*DV_+d];
  #pragma unroll
  for(int c=1;c<CHK;++c){
    unsigned vE = ABu[((size_t)(b*(CHK-1) + (c-1))*MEM_ + 2*p)*DV_ + d];
    unsigned vO = ABu[((size_t)(b*(CHK-1) + (c-1))*MEM_ + 2*p+1)*DV_ + d];
    MvE = fmaf((float)h2(vE)[0], MvE, (float)h2(vE)[1]);
    MvO = fmaf((float)h2(vO)[0], MvO, (float)h2(vO)[1]);
    Mv0p[((size_t)(b*CHK + c)*(MEM_/2) + p)*DV_ + d] = packh2(MvE, MvO);
  }
}

// K3: fused phase-2 scan (f16 pk-fma + v_dot2 f32-acc) + MFMA readout + epilogue.
// ROLLED loop unroll 4 (r13: full unroll spills). Scan state dies before MFMA
// phase (r10: overlapping lifetimes spill). Plain per-block partial stores —
// NO atomics/fences (r6/r7: per-block device-scope fences nuke per-XCD L2).
__global__ __launch_bounds__(256,8) void k_scan_mm(const int* __restrict__ qd,
    const int* __restrict__ qad,
    const unsigned* __restrict__ corrH,
    const uint2* __restrict__ eaTab,
    const float* __restrict__ mv0,
    const unsigned* __restrict__ Mv0p,
    const unsigned short* __restrict__ WpFrag,
    const float* __restrict__ hq,
    const float* __restrict__ pwPad, const float* __restrict__ pb,
    const float* __restrict__ target,
    float* __restrict__ out, float2* __restrict__ partials){
  __shared__ unsigned short Xs[CLEN*XS_STRIDE];   // 14,848 B
  __shared__ float sred[2][2][16];
  __shared__ float sbce[4];

  const int blk = blockIdx.x;
  const int b = blk >> 4, c = blk & (CHK-1);
  const int d = threadIdx.x;
  const int dc = (d < DV_) ? d : DV_-1;
  const bool act = (d < DV_);
  const bool padw = (d < 224);
  const int* __restrict__ qp  = qd  + b*S_ + c*CLEN;
  const int* __restrict__ qap = qad + b*S_ + c*CLEN;

  const int wave = threadIdx.x >> 6;
  const int lane = threadIdx.x & 63;
  const int col  = lane & 15, quad = lane >> 4;
  const int rt   = wave & 1;
  const int nh   = wave >> 1;
  const int mbase = rt*16;

  int qpre[4];
  #pragma unroll
  for(int reg=0;reg<4;++reg) qpre[reg] = qp[mbase + quad*4 + reg];

  f16x2_t Mv2[MEM_/2];
  if(c == 0){
    #pragma unroll
    for(int i=0;i<MEM_/2;++i)
      Mv2[i] = (f16x2_t){ (_Float16)mv0[(2*i)*DV_+dc], (_Float16)mv0[(2*i+1)*DV_+dc] };
  } else {
    const unsigned* base = Mv0p + ((size_t)(b*CHK + c)*(MEM_/2))*DV_ + dc;
    #pragma unroll
    for(int i=0;i<MEM_/2;++i)
      Mv2[i] = h2(base[(size_t)i*DV_]);
  }

  int q2   = qp[1];
  int qaT2 = qap[2];
  int qaT3 = qap[3];
  int q1s  = __builtin_amdgcn_readfirstlane(qp[0]);
  const unsigned* cp0 = corrH + q1s*CORR_STRIDE;
  uint4 ca = *(const uint4*)(cp0);
  uint4 cb = *(const uint4*)(cp0+4);
  uint2 cc = *(const uint2*)(cp0+8);
  uint2 ea  = eaTab[(size_t)qap[0]*DV_ + dc];
  uint2 ean = eaTab[(size_t)qap[1]*DV_ + dc];

  #pragma unroll 4
  for(int t=0;t<CLEN;++t){
    int t2 = (t+2 < CLEN) ? t+2 : CLEN-1;
    int t4 = (t+4 < CLEN) ? t+4 : CLEN-1;
    int q3 = qp[t2];
    int qaN = qap[t4];
    int qs = __builtin_amdgcn_readfirstlane(q2);
    const unsigned* cpn_ = corrH + qs*CORR_STRIDE;
    uint4 na = *(const uint4*)(cpn_);
    uint4 nb = *(const uint4*)(cpn_+4);
    uint2 nc = *(const uint2*)(cpn_+8);
    uint2 eann = eaTab[(size_t)qaT2*DV_ + dc];

    const f16x2_t ee = h2(ea.x), aa = h2(ea.y);
    float rd0 = 0.f, rd1 = 0.f;
    #define UPD2(u, i, acc) { \
      f16x2_t cp = h2(u); \
      acc = __builtin_amdgcn_fdot2(cp, Mv2[i], acc, false); \
      f16x2_t tt = pkfma16(-Mv2[i], ee, aa); \
      Mv2[i] = pkfma16(cp, tt, Mv2[i]); }
    UPD2(ca.x, 0, rd0)  UPD2(ca.y, 1, rd1)  UPD2(ca.z, 2, rd0)  UPD2(ca.w, 3, rd1)
    UPD2(cb.x, 4, rd0)  UPD2(cb.y, 5, rd1)  UPD2(cb.z, 6, rd0)  UPD2(cb.w, 7, rd1)
    UPD2(cc.x, 8, rd0)  UPD2(cc.y, 9, rd1)
    #undef UPD2

    if(padw) Xs[t*XS_STRIDE + d] = act ? f2bf(rd0+rd1) : (unsigned short)0;

    ca=na; cb=nb; cc=nc;
    ea=ean; ean=eann;
    q2=q3; qaT2=qaT3; qaT3=qaN;
  }
  __syncthreads();

  // hq prefetch — issued before the MFMA loop so the 14 MFMAs hide the latency
  float hqv[4][2];
  #pragma unroll
  for(int reg=0;reg<4;++reg)
    #pragma unroll
    for(int j=0;j<2;++j)
      hqv[reg][j] = hq[qpre[reg]*64 + (nh*2+j)*16 + col];

  f32x4_t acc[2];
  acc[0] = (f32x4_t){0.f,0.f,0.f,0.f};
  acc[1] = (f32x4_t){0.f,0.f,0.f,0.f};

  #pragma unroll
  for(int ks=0;ks<NKS;++ks){
    bf16x8_t a = *reinterpret_cast<const bf16x8_t*>(Xs + (mbase+col)*XS_STRIDE + quad*8 + ks*32);
    #pragma unroll
    for(int j=0;j<2;++j){
      int nt = nh*2 + j;
      bf16x8_t bfr = *reinterpret_cast<const bf16x8_t*>(WpFrag + ((size_t)(ks*4+nt)*64 + lane)*8);
      acc[j] = __builtin_amdgcn_mfma_f32_16x16x32_bf16(a, bfr, acc[j], 0, 0, 0);
    }
  }

  float part[4];
  #pragma unroll
  for(int reg=0;reg<4;++reg){
    float s = 0.f;
    #pragma unroll
    for(int j=0;j<2;++j){
      int n = (nh*2+j)*16 + col;
      float h = acc[j][reg] + hqv[reg][j];
      s = fmaf(pwPad[n], ftanh(h), s);
    }
    part[reg] = s;
  }
  #pragma unroll
  for(int off=1; off<16; off<<=1){
    #pragma unroll
    for(int reg=0;reg<4;++reg) part[reg] += __shfl_xor(part[reg], off, 64);
  }
  if(col == 0){
    #pragma unroll
    for(int reg=0;reg<4;++reg) sred[rt][nh][quad*4+reg] = part[reg];
  }
  __syncthreads();

  float bce = 0.f, cnt = 0.f;
  if(nh == 0 && col == 0){
    float pbv = pb[0];
    #pragma unroll
    for(int reg=0;reg<4;++reg){
      int idx = quad*4 + reg;
      int mloc = mbase + idx;
      int row = b*S_ + c*CLEN + mloc;
      float logit = sred[rt][0][idx] + sred[rt][1][idx] + pbv;
      out[1+row] = fsigm(logit);
      float t = target[row];
      if(t >= 0.f){
        cnt += 1.f;
        bce += fmaxf(logit,0.f) - logit*t + log1pf(__expf(-fabsf(logit)));
      }
    }
  }
  bce += __shfl_xor(bce, 16, 64); cnt += __shfl_xor(cnt, 16, 64);
  bce += __shfl_xor(bce, 32, 64); cnt += __shfl_xor(cnt, 32, 64);
  if(lane == 0 && nh == 0){ sbce[wave] = bce; sbce[2+wave] = cnt; }
  __syncthreads();
  if(threadIdx.x == 0)
    partials[blk] = make_float2(sbce[0]+sbce[1], sbce[2]+sbce[3]);
}

// K4: reduce per-block partials -> loss
__global__ __launch_bounds__(256) void k_fin(const float2* __restrict__ partials,
                                             float* __restrict__ out){
  float bce = 0.f, cnt = 0.f;
  for(int i=threadIdx.x; i<MM_BLOCKS; i+=256){
    float2 p = partials[i];
    bce += p.x; cnt += p.y;
  }
  #pragma unroll
  for(int off=32; off>0; off>>=1){
    bce += __shfl_down(bce, off, 64);
    cnt += __shfl_down(cnt, off, 64);
  }
  __shared__ float sb[4], sc[4];
  int w = threadIdx.x >> 6;
  if((threadIdx.x & 63) == 0){ sb[w] = bce; sc[w] = cnt; }
  __syncthreads();
  if(threadIdx.x == 0){
    float Bt = sb[0]+sb[1]+sb[2]+sb[3];
    float Ct = sc[0]+sc[1]+sc[2]+sc[3];
    out[0] = Bt / fmaxf(Ct, 1.f);
  }
}

extern "C" void kernel_launch(void* const* d_in, const int* in_sizes, int n_in,
                              void* d_out, int out_size, void* d_ws, size_t ws_size,
                              hipStream_t stream){
  const int*   qd     = (const int*)d_in[0];
  const int*   qad    = (const int*)d_in[1];
  const float* target = (const float*)d_in[2];
  const float* qw     = (const float*)d_in[3];
  const float* qaw    = (const float*)d_in[4];
  const float* mk     = (const float*)d_in[5];
  const float* mv0    = (const float*)d_in[6];
  const float* ew     = (const float*)d_in[7];
  const float* eb     = (const float*)d_in[8];
  const float* aw     = (const float*)d_in[9];
  const float* ab     = (const float*)d_in[10];
  const float* rw     = (const float*)d_in[11];
  const float* rb     = (const float*)d_in[12];
  const float* pw     = (const float*)d_in[13];
  const float* pb     = (const float*)d_in[14];
  float* out = (float*)d_out;

  char* ws = (char*)d_ws;
  size_t off = 0;
  float2* partials = (float2*)(ws + off);            off += (size_t)MM_BLOCKS*8;
  unsigned* corrH = (unsigned*)(ws + off);           off += (((size_t)(NQ_+1)*CORR_STRIDE*4 + 255)/256)*256;
  uint2* eaTab    = (uint2*)(ws + off);              off += (((size_t)(2*NQ_+1)*DV_*8 + 255)/256)*256;
  unsigned* ABu   = (unsigned*)(ws + off);           off += (size_t)SCANA_BLOCKS*MEM_*DV_*4;
  unsigned* Mv0p  = (unsigned*)(ws + off);           off += (size_t)MM_BLOCKS*(MEM_/2)*DV_*4;
  unsigned short* WpFrag = (unsigned short*)(ws + off); off += ((size_t)NKS*4*64*8*2 + 255)/256*256;
  float* pwPad    = (float*)(ws + off);              off += 256;
  float* hq       = (float*)(ws + off);              off += (size_t)(NQ_+1)*64*4;

  k_prep1<<<dim3(PREP1_BLOCKS), dim3(256), 0, stream>>>(qaw, ew, eb, aw, ab, eaTab,
                                                        qw, mk, corrH);
  k_scanA<<<dim3(SCANA_TOTAL), dim3(256), 0, stream>>>(qd, qad, corrH, eaTab,
                                                       ABu, qw, rw, rb, pw, WpFrag, pwPad, hq);
  k_prefix<<<dim3((B_*(MEM_/2)*DV_+255)/256), dim3(256), 0, stream>>>(mv0, ABu, Mv0p);
  k_scan_mm<<<dim3(MM_BLOCKS), dim3(256), 0, stream>>>(qd, qad, corrH, eaTab,
                                                       mv0, Mv0p, WpFrag, hq, pwPad, pb, target, out, partials);
  k_fin<<<dim3(1), dim3(256), 0, stream>>>(partials, out);
}